// Round 11
// baseline (561.561 us; speedup 1.0000x reference)
//
#include <hip/hip_runtime.h>
#include <math.h>

#define NPT 2048
#define BB 4
#define KNN 20
#define EPSV 1e-6f

typedef unsigned short u16;
typedef unsigned int u32;
typedef __attribute__((ext_vector_type(8))) short short8;
typedef __attribute__((ext_vector_type(4))) float f32x4;
typedef __attribute__((ext_vector_type(4))) u32 uint4v;

#define MFMA16(a,b,c) __builtin_amdgcn_mfma_f32_16x16x32_bf16((a),(b),(c),0,0,0)

__device__ __forceinline__ u16 f2bh(float f) {
    u32 u = __builtin_bit_cast(u32, f);
    return (u16)((u + 0x7FFFu + ((u >> 16) & 1u)) >> 16);
}
__device__ __forceinline__ float bh2f(u32 hbits) {
    return __builtin_bit_cast(float, hbits << 16);
}

// ------------------------------------------------ kNN top-20 via radix-select
// (round-7 version, verbatim — passed)
__global__ __launch_bounds__(256)
void knn_kernel(const float* __restrict__ p, int* __restrict__ idx) {
    int bn = blockIdx.x;
    int b = bn >> 11, n = bn & (NPT - 1);
    const float* pb = p + (size_t)b * NPT * 3;
    float qx = pb[n*3+0], qy = pb[n*3+1], qz = pb[n*3+2];
    float qq = qx*qx + qy*qy + qz*qz;
    __shared__ u32 keys[NPT];
    __shared__ int hist[4][256];
    __shared__ int wtot[4];
    __shared__ int sh_byte, sh_ngt, sure_cnt, tie_cnt;
    __shared__ int tie_m[64];
    int tid = threadIdx.x;
    int lane = tid & 63, wv = tid >> 6;
    for (int m = tid; m < NPT; m += 256) {
        float px = pb[m*3+0], py = pb[m*3+1], pz = pb[m*3+2];
        float sc = 2.f*(qx*px + qy*py + qz*pz) - qq - (px*px + py*py + pz*pz);
        u32 u = __builtin_bit_cast(u32, sc);
        keys[m] = u ^ (u32)(((int)u >> 31) | (int)0x80000000);
    }
    if (tid == 0) { sure_cnt = 0; tie_cnt = 0; }
    __syncthreads();
    u32 prefix = 0; int need = KNN;
    for (int pass = 3; pass >= 0; --pass) {
        int shift = pass * 8;
        u32 maskhi = (pass == 3) ? 0u : (0xFFFFFFFFu << (shift + 8));
        hist[0][tid] = 0; hist[1][tid] = 0; hist[2][tid] = 0; hist[3][tid] = 0;
        __syncthreads();
        int prevbin = -1, cnt = 0;
        #pragma unroll
        for (int j = 0; j < 8; ++j) {
            u32 key = keys[tid + 256*j];
            int bin = ((key & maskhi) == (prefix & maskhi)) ? (int)((key >> shift) & 255) : -1;
            if (bin == prevbin) { ++cnt; }
            else {
                if (prevbin >= 0) atomicAdd(&hist[wv][prevbin], cnt);
                prevbin = bin; cnt = 1;
            }
        }
        if (prevbin >= 0) atomicAdd(&hist[wv][prevbin], cnt);
        __syncthreads();
        int own = hist[0][tid] + hist[1][tid] + hist[2][tid] + hist[3][tid];
        int sum = own;
        #pragma unroll
        for (int off = 1; off < 64; off <<= 1) {
            int v = __shfl_down(sum, off, 64);
            if (lane + off < 64) sum += v;
        }
        if (lane == 0) wtot[wv] = sum;
        __syncthreads();
        int addhi = 0;
        #pragma unroll
        for (int w2 = 0; w2 < 4; ++w2) if (w2 > wv) addhi += wtot[w2];
        int cnt_ge = sum + addhi;
        int cnt_gt = cnt_ge - own;
        if (cnt_ge >= need && cnt_gt < need) { sh_byte = tid; sh_ngt = cnt_gt; }
        __syncthreads();
        prefix |= ((u32)sh_byte) << shift;
        need -= sh_ngt;
        __syncthreads();
    }
    u32 T = prefix;
    #pragma unroll
    for (int j = 0; j < 8; ++j) {
        int m = tid + 256*j;
        u32 key = keys[m];
        if (key > T) {
            int slot = atomicAdd(&sure_cnt, 1);
            idx[(size_t)bn*KNN + slot] = m;
        } else if (key == T) {
            int t = atomicAdd(&tie_cnt, 1);
            if (t < 64) tie_m[t] = m;
        }
    }
    __syncthreads();
    if (tid == 0) {
        int base = sure_cnt;
        int r = KNN - base;
        int tc = tie_cnt;
        if (tc == r) {
            for (int t2 = 0; t2 < r; ++t2) idx[(size_t)bn*KNN + base + t2] = tie_m[t2];
        } else if (tc <= 64) {
            for (int t2 = 0; t2 < r; ++t2) {
                int best = 1 << 30, bj = 0;
                for (int t3 = 0; t3 < tc; ++t3)
                    if (tie_m[t3] < best) { best = tie_m[t3]; bj = t3; }
                tie_m[bj] = 1 << 30;
                idx[(size_t)bn*KNN + base + t2] = best;
            }
        } else {
            int got = 0;
            for (int m = 0; m < NPT && got < r; ++m)
                if (keys[m] == T) { idx[(size_t)bn*KNN + base + got] = m; ++got; }
        }
    }
}

// ---------------------- edge conv + leaky(0.2) + mean_k -> split-bf16 K-major
__global__ __launch_bounds__(128)
void edgeconv_kernel(const float* __restrict__ p, const int* __restrict__ idx,
                     const float* __restrict__ wf, const float* __restrict__ wd,
                     u16* __restrict__ net1h, u16* __restrict__ net1l) {
    int bn = blockIdx.x;
    int b = bn >> 11, n = bn & (NPT - 1);
    __shared__ float nb[KNN][3];
    __shared__ float ctr[3];
    int tid = threadIdx.x;
    if (tid < KNN) {
        int j = idx[(size_t)bn*KNN + tid];
        const float* pj = p + ((size_t)b*NPT + j)*3;
        nb[tid][0] = pj[0]; nb[tid][1] = pj[1]; nb[tid][2] = pj[2];
    }
    if (tid >= 64 && tid < 67) ctr[tid-64] = p[((size_t)b*NPT + n)*3 + (tid-64)];
    __syncthreads();
    int o = tid;
    float wfa = wf[o*3+0], wfb = wf[o*3+1], wfc = wf[o*3+2];
    float wda = wd[o*3+0], wdb = wd[o*3+1], wdc = wd[o*3+2];
    float cx = ctr[0], cy = ctr[1], cz = ctr[2];
    float a0 = 0.f, a1 = 0.f, a2 = 0.f;
    #pragma unroll 4
    for (int k = 0; k < KNN; ++k) {
        float nx = nb[k][0], ny = nb[k][1], nz = nb[k][2];
        float rx = nx-cx, ry = ny-cy, rz = nz-cz;
        float sx = ny*cz - nz*cy;
        float sy = nz*cx - nx*cz;
        float sz = nx*cy - ny*cx;
        float fx = wfa*rx + wfb*cx + wfc*sx;
        float fy = wfa*ry + wfb*cy + wfc*sy;
        float fz = wfa*rz + wfb*cz + wfc*sz;
        float dx0 = wda*rx + wdb*cx + wdc*sx;
        float dy0 = wda*ry + wdb*cy + wdc*sy;
        float dz0 = wda*rz + wdb*cz + wdc*sz;
        float dot = fx*dx0 + fy*dy0 + fz*dz0;
        float dsq = dx0*dx0 + dy0*dy0 + dz0*dz0;
        float t = dot / (dsq + EPSV);
        bool pos = dot >= 0.f;
        float gx = pos ? fx : (fx - t*dx0);
        float gy = pos ? fy : (fy - t*dy0);
        float gz = pos ? fz : (fz - t*dz0);
        a0 += 0.2f*fx + 0.8f*gx;
        a1 += 0.2f*fy + 0.8f*gy;
        a2 += 0.2f*fz + 0.8f*gz;
    }
    const float s = 1.f / (float)KNN;
    float av[3] = {a0*s, a1*s, a2*s};
    #pragma unroll
    for (int v = 0; v < 3; ++v) {
        u16 h = f2bh(av[v]);
        u16 l = f2bh(av[v] - bh2f(h));
        size_t off = (size_t)(b*6144 + v*2048 + n)*128 + o;
        net1h[off] = h; net1l[off] = l;
    }
}

// ------------------------------------------------------ MFMA split-bf16 GEMM
// LDS-free K-loop: A-fragments from pre-swizzled W, B-fragments direct from
// K-major X. No barriers until the epilogue transpose. Tile 128o x 64m.
template<int O, int C1, int C2, bool POOL, bool BIASED>
__global__ __launch_bounds__(256) void gemm_plain(
    const u16* __restrict__ W1h, const u16* __restrict__ W1l, int ldw1,
    const u16* __restrict__ X1h, const u16* __restrict__ X1l, int sx1,
    const u16* __restrict__ W2h, const u16* __restrict__ W2l, int ldw2,
    const u16* __restrict__ X2h, const u16* __restrict__ X2l, int sx2,
    const float* __restrict__ WscF, const float* __restrict__ PmPrev,
    u16* __restrict__ Yh, u16* __restrict__ Yl, int sy,
    float* __restrict__ PmOut)
{
    __shared__ __align__(16) float sd[64*132];
    __shared__ float pms[128];
    __shared__ float biasS_s[128];
    const int m0 = blockIdx.x * 64;
    const int ob = blockIdx.y * 128;
    const int b   = m0 / 6144;
    const int vec = (m0 % 6144) / 2048;
    const int tid = threadIdx.x;
    const int lane = tid & 63;
    const int wid = __builtin_amdgcn_readfirstlane(tid >> 6);
    const int wr = wid & 1, wc = wid >> 1;          // wr: o-half(64), wc: m-half(32)
    const int l15 = lane & 15, l4 = lane >> 4;

    if (BIASED) {
        if (tid < 128) pms[tid] = PmPrev[(size_t)(b*128 + tid)*3 + vec];
        __syncthreads();
        if (tid < 128) {
            const float* wrow = WscF + (size_t)tid*256 + 128;
            float s = 0.f;
            #pragma unroll 4
            for (int c = 0; c < 128; ++c) s += wrow[c]*pms[c];
            biasS_s[tid] = s;
        }
        __syncthreads();
    }

    f32x4 acc[4][2];
    #pragma unroll
    for (int io = 0; io < 4; ++io) {
        float bv[4];
        #pragma unroll
        for (int r = 0; r < 4; ++r)
            bv[r] = BIASED ? biasS_s[wr*64 + io*16 + l4*4 + r] : 0.f;
        #pragma unroll
        for (int jc = 0; jc < 2; ++jc)
            #pragma unroll
            for (int r = 0; r < 4; ++r) acc[io][jc][r] = bv[r];
    }

    constexpr int NS = C1/32 + C2/32;
    #pragma unroll 2
    for (int st = 0; st < NS; ++st) {
        const bool ph2 = (st >= C1/32);
        const u16* wh = ph2 ? W2h : W1h; const u16* wl = ph2 ? W2l : W1l;
        const u16* xh = ph2 ? X2h : X1h; const u16* xl = ph2 ? X2l : X1l;
        int ldw = ph2 ? ldw2 : ldw1; int sx = ph2 ? sx2 : sx1;
        int stl = ph2 ? (st - C1/32) : st;
        int cc = stl * 32;
        short8 fAh[4], fAl[4], fBh[2], fBl[2];
        #pragma unroll
        for (int io = 0; io < 4; ++io) {
            int oT = ob + wr*64 + io*16;
            size_t wo_ = ((size_t)((oT >> 4)*(ldw >> 3) + stl*4 + l4))*128 + l15*8;
            fAh[io] = *reinterpret_cast<const short8*>(wh + wo_);
            fAl[io] = *reinterpret_cast<const short8*>(wl + wo_);
        }
        #pragma unroll
        for (int i = 0; i < 2; ++i) {
            int rb = wc*32 + i*16 + l15;
            size_t xo = (size_t)(m0 + rb)*sx + cc + l4*8;
            fBh[i] = *reinterpret_cast<const short8*>(xh + xo);
            fBl[i] = *reinterpret_cast<const short8*>(xl + xo);
        }
        #pragma unroll
        for (int io = 0; io < 4; ++io)
            #pragma unroll
            for (int jc = 0; jc < 2; ++jc) {
                acc[io][jc] = MFMA16(fAl[io], fBh[jc], acc[io][jc]);
                acc[io][jc] = MFMA16(fAh[io], fBl[jc], acc[io][jc]);
                acc[io][jc] = MFMA16(fAh[io], fBh[jc], acc[io][jc]);
            }
    }

    #pragma unroll
    for (int io = 0; io < 4; ++io)
        #pragma unroll
        for (int jc = 0; jc < 2; ++jc) {
            int jj = wc*32 + jc*16 + l15;
            int orow = wr*64 + io*16 + l4*4;
            *reinterpret_cast<f32x4*>(sd + jj*132 + orow) = acc[io][jc];
        }
    __syncthreads();

    #pragma unroll
    for (int rep = 0; rep < 4; ++rep) {
        int task = tid + 256*rep;
        int oc = task & 15, ml = task >> 4;          // ml in [0,64)
        const float* dp = sd + ml*132 + oc*8;
        u32 hw[4], lw[4];
        #pragma unroll
        for (int e2 = 0; e2 < 4; ++e2) {
            float y0 = dp[2*e2], y1 = dp[2*e2+1];
            u16 h0 = f2bh(y0), h1 = f2bh(y1);
            u16 q0 = f2bh(y0 - bh2f(h0)), q1 = f2bh(y1 - bh2f(h1));
            hw[e2] = (u32)h0 | ((u32)h1 << 16);
            lw[e2] = (u32)q0 | ((u32)q1 << 16);
        }
        size_t ooff = (size_t)(m0 + ml)*sy + ob + oc*8;
        *reinterpret_cast<uint4v*>(Yh + ooff) = (uint4v){hw[0],hw[1],hw[2],hw[3]};
        *reinterpret_cast<uint4v*>(Yl + ooff) = (uint4v){lw[0],lw[1],lw[2],lw[3]};
    }

    if (POOL) {
        int o_l = tid & 127, half = tid >> 7;        // 2 halves x 32 cols
        float sum = 0.f;
        #pragma unroll 8
        for (int c = 0; c < 32; ++c) sum += sd[(half*32 + c)*132 + o_l];
        atomicAdd(&PmOut[(size_t)(b*128 + o_l)*3 + vec], sum * (1.f/(float)NPT));
    }
}

// ------------------- MFMA split-bf16 dir GEMM + fused VN-leaky(0) epilogue
// LDS-free K-loop (pre-swizzled W + direct X fragments); LDS epilogue only.
template<int O, int CIN, bool VIRT>
__global__ __launch_bounds__(256) void gemm_dir(
    const u16* __restrict__ Wh_, const u16* __restrict__ Wl_, int ldw,
    const u16* __restrict__ X1h, const u16* __restrict__ X1l, int sx,
    const float* __restrict__ WdF, const float* __restrict__ Pm,
    u16* __restrict__ Oh, u16* __restrict__ Ol, int so,
    float* __restrict__ PmZero)
{
    __shared__ __align__(16) float sd[96*132];
    __shared__ float pmd[384];
    __shared__ float biasD_s[384];
    const int gx = blockIdx.x;
    const int b  = gx >> 6;
    const int n0 = (gx & 63) * 32;
    const int ob = blockIdx.y * 128;
    const int tid = threadIdx.x;
    const int lane = tid & 63;
    const int wid = __builtin_amdgcn_readfirstlane(tid >> 6);
    const int wr = wid & 1, wc = wid >> 1;
    const int l15 = lane & 15, l4 = lane >> 4;

    if (PmZero != nullptr && gx == 0 && blockIdx.y == 0)
        for (int t = tid; t < 1536; t += 256) PmZero[t] = 0.f;   // ALL batches

    if (VIRT) {
        for (int t = tid; t < 384; t += 256) pmd[t] = Pm[(size_t)b*384 + t];
        __syncthreads();
        for (int t = tid; t < 384; t += 256) {
            int o_l = t / 3, v = t - o_l*3;
            const float* wrow = WdF + (size_t)(ob + o_l)*256 + 128;
            float s = 0.f;
            #pragma unroll 4
            for (int c = 0; c < 128; ++c) s += wrow[c]*pmd[c*3 + v];
            biasD_s[t] = s;
        }
        __syncthreads();
    }

    f32x4 acc[4][3];
    #pragma unroll
    for (int io = 0; io < 4; ++io)
        #pragma unroll
        for (int jc = 0; jc < 3; ++jc) {
            int v = (wc*48 + jc*16) >> 5;
            #pragma unroll
            for (int r = 0; r < 4; ++r) {
                int o_l = wr*64 + io*16 + l4*4 + r;
                acc[io][jc][r] = VIRT ? biasD_s[o_l*3 + v] : 0.f;
            }
        }

    constexpr int NS = CIN/32;
    #pragma unroll 2
    for (int st = 0; st < NS; ++st) {
        int cc = st * 32;
        short8 fAh[4], fAl[4], fBh[3], fBl[3];
        #pragma unroll
        for (int io = 0; io < 4; ++io) {
            int oT = ob + wr*64 + io*16;
            size_t wo_ = ((size_t)((oT >> 4)*(ldw >> 3) + st*4 + l4))*128 + l15*8;
            fAh[io] = *reinterpret_cast<const short8*>(Wh_ + wo_);
            fAl[io] = *reinterpret_cast<const short8*>(Wl_ + wo_);
        }
        #pragma unroll
        for (int i = 0; i < 3; ++i) {
            int rb = wc*48 + i*16 + l15;
            int m = b*6144 + (rb >> 5)*2048 + n0 + (rb & 31);
            size_t xo = (size_t)m*sx + cc + l4*8;
            fBh[i] = *reinterpret_cast<const short8*>(X1h + xo);
            fBl[i] = *reinterpret_cast<const short8*>(X1l + xo);
        }
        #pragma unroll
        for (int io = 0; io < 4; ++io)
            #pragma unroll
            for (int jc = 0; jc < 3; ++jc) {
                acc[io][jc] = MFMA16(fAl[io], fBh[jc], acc[io][jc]);
                acc[io][jc] = MFMA16(fAh[io], fBl[jc], acc[io][jc]);
                acc[io][jc] = MFMA16(fAh[io], fBh[jc], acc[io][jc]);
            }
    }

    #pragma unroll
    for (int io = 0; io < 4; ++io)
        #pragma unroll
        for (int jc = 0; jc < 3; ++jc) {
            int jj = wc*48 + jc*16 + l15;
            int orow = wr*64 + io*16 + l4*4;
            *reinterpret_cast<f32x4*>(sd + jj*132 + orow) = acc[io][jc];
        }
    __syncthreads();

    #pragma unroll
    for (int rep = 0; rep < 2; ++rep) {
        int task = tid + 256*rep;
        int oc = task & 15, nl = (task >> 4) & 31;
        float d[3][8], x[3][8];
        #pragma unroll
        for (int v = 0; v < 3; ++v) {
            const float* dp = sd + (v*32 + nl)*132 + oc*8;
            #pragma unroll
            for (int e = 0; e < 8; ++e) d[v][e] = dp[e];
        }
        if (VIRT && ob != 0) {
            #pragma unroll
            for (int e = 0; e < 8; ++e) {
                int c = oc*8 + e;
                #pragma unroll
                for (int v = 0; v < 3; ++v)
                    x[v][e] = Pm[(size_t)(b*128 + c)*3 + v];
            }
        } else {
            #pragma unroll
            for (int v = 0; v < 3; ++v) {
                size_t m = (size_t)(b*6144 + v*2048 + n0 + nl);
                uint4v hx = *reinterpret_cast<const uint4v*>(X1h + m*sx + ob + oc*8);
                uint4v lx = *reinterpret_cast<const uint4v*>(X1l + m*sx + ob + oc*8);
                #pragma unroll
                for (int w = 0; w < 4; ++w) {
                    x[v][2*w]   = bh2f(hx[w] & 0xffffu) + bh2f(lx[w] & 0xffffu);
                    x[v][2*w+1] = bh2f(hx[w] >> 16)     + bh2f(lx[w] >> 16);
                }
            }
        }
        #pragma unroll
        for (int e = 0; e < 8; ++e) {
            float d0 = d[0][e], d1 = d[1][e], d2 = d[2][e];
            float dot = x[0][e]*d0 + x[1][e]*d1 + x[2][e]*d2;
            float dsq = d0*d0 + d1*d1 + d2*d2;
            float t = dot / (dsq + EPSV);
            if (dot < 0.f) { x[0][e] -= t*d0; x[1][e] -= t*d1; x[2][e] -= t*d2; }
        }
        #pragma unroll
        for (int v = 0; v < 3; ++v) {
            u32 hw[4], lw[4];
            #pragma unroll
            for (int e2 = 0; e2 < 4; ++e2) {
                float y0 = x[v][2*e2], y1 = x[v][2*e2+1];
                u16 h0 = f2bh(y0), h1 = f2bh(y1);
                u16 q0 = f2bh(y0 - bh2f(h0)), q1 = f2bh(y1 - bh2f(h1));
                hw[e2] = (u32)h0 | ((u32)h1 << 16);
                lw[e2] = (u32)q0 | ((u32)q1 << 16);
            }
            size_t ooff = (size_t)(b*6144 + v*2048 + n0 + nl)*so + ob + oc*8;
            *reinterpret_cast<uint4v*>(Oh + ooff) = (uint4v){hw[0],hw[1],hw[2],hw[3]};
            *reinterpret_cast<uint4v*>(Ol + ooff) = (uint4v){lw[0],lw[1],lw[2],lw[3]};
        }
    }
}

// -------------------------- weight split-bf16 convert + A-fragment swizzle
// dst layout per matrix (row length K): [o/16][k/8][o&15][k&7] — a wave's
// A-fragment (16 rows x 8 k x 16B lanes) is 1KB contiguous.
#define WO_FCPOS 0
#define WO_DIR0  32768
#define WO_FC0   360448
#define WO_DIR1  524288
#define WO_FC1   606208
#define WO_SC    688128
#define WTOT     851968
__global__ __launch_bounds__(256)
void convert_w_kernel(const float* __restrict__ s0, const float* __restrict__ s1,
                      const float* __restrict__ s2, const float* __restrict__ s3,
                      const float* __restrict__ s4, const float* __restrict__ s5,
                      u16* __restrict__ Wh, u16* __restrict__ Wl) {
    int t = blockIdx.x*256 + threadIdx.x;
    if (t >= WTOT) return;
    const float* src; int base; int ksh;   // ksh = log2(K)
    if      (t < WO_DIR0) { src = s0; base = WO_FCPOS; ksh = 7; }
    else if (t < WO_FC0)  { src = s1; base = WO_DIR0;  ksh = 8; }
    else if (t < WO_DIR1) { src = s2; base = WO_FC0;   ksh = 8; }
    else if (t < WO_FC1)  { src = s3; base = WO_DIR1;  ksh = 7; }
    else if (t < WO_SC)   { src = s4; base = WO_FC1;   ksh = 7; }
    else                  { src = s5; base = WO_SC;    ksh = 8; }
    int r = t - base;
    int o = r >> ksh;
    int k = r & ((1 << ksh) - 1);
    float v = src[r];
    u16 h = f2bh(v);
    int dst = base + (((o >> 4) << (ksh - 3)) + (k >> 3))*128 + ((o & 15) << 3) + (k & 7);
    Wh[dst] = h;
    Wl[dst] = f2bh(v - bh2f(h));
}

// ----------------------------------------------------- head: leaky(0.2)+fc_c
__global__ __launch_bounds__(128)
void final_head_kernel(const float* __restrict__ q, const float* __restrict__ Wdir,
                       const float* __restrict__ Wfc, float* __restrict__ out) {
    int b = blockIdx.x; int o = threadIdx.x;
    __shared__ float qs[128][3];
    __shared__ float zs[128][3];
    qs[o][0] = q[((size_t)b*128 + o)*3 + 0];
    qs[o][1] = q[((size_t)b*128 + o)*3 + 1];
    qs[o][2] = q[((size_t)b*128 + o)*3 + 2];
    __syncthreads();
    float d0 = 0.f, d1 = 0.f, d2 = 0.f;
    for (int c = 0; c < 128; ++c) {
        float w = Wdir[o*128 + c];
        d0 += w*qs[c][0]; d1 += w*qs[c][1]; d2 += w*qs[c][2];
    }
    float x0 = qs[o][0], x1 = qs[o][1], x2 = qs[o][2];
    float dot = d0*x0 + d1*x1 + d2*x2;
    float dsq = d0*d0 + d1*d1 + d2*d2;
    float t = dot / (dsq + EPSV);
    bool pos = dot >= 0.f;
    float g0 = pos ? x0 : (x0 - t*d0);
    float g1 = pos ? x1 : (x1 - t*d1);
    float g2 = pos ? x2 : (x2 - t*d2);
    zs[o][0] = 0.2f*x0 + 0.8f*g0;
    zs[o][1] = 0.2f*x1 + 0.8f*g1;
    zs[o][2] = 0.2f*x2 + 0.8f*g2;
    __syncthreads();
    float c0 = 0.f, c1 = 0.f, c2 = 0.f;
    for (int c = 0; c < 128; ++c) {
        float w = Wfc[o*128 + c];
        c0 += w*zs[c][0]; c1 += w*zs[c][1]; c2 += w*zs[c][2];
    }
    out[((size_t)b*128 + o)*3 + 0] = c0;
    out[((size_t)b*128 + o)*3 + 1] = c1;
    out[((size_t)b*128 + o)*3 + 2] = c2;
}

extern "C" void kernel_launch(void* const* d_in, const int* in_sizes, int n_in,
                              void* d_out, int out_size, void* d_ws, size_t ws_size,
                              hipStream_t stream) {
    const float* p           = (const float*)d_in[0];
    const float* w_conv_feat = (const float*)d_in[1];
    const float* w_conv_dir  = (const float*)d_in[2];
    const float* w_fc_pos    = (const float*)d_in[3];
    const float* blk_dir0    = (const float*)d_in[4];
    const float* blk_fc0     = (const float*)d_in[5];
    const float* blk_dir1    = (const float*)d_in[6];
    const float* blk_fc1     = (const float*)d_in[7];
    const float* blk_sc      = (const float*)d_in[8];
    const float* w_actc_dir  = (const float*)d_in[9];
    const float* w_fc_c      = (const float*)d_in[10];
    float* out = (float*)d_out;

    char* wsb = (char*)d_ws;
    size_t cur = 0;
    auto carve = [&](size_t nbytes) -> char* {
        char* r = wsb + cur;
        cur += (nbytes + 255) & ~(size_t)255;
        return r;
    };
    const size_t MTOT = (size_t)BB*3*NPT;      // 24576 columns
    int*   idx   = (int*)  carve((size_t)BB*NPT*KNN*4);
    float* Pm0   = (float*)carve(1536*4);
    float* Pm1   = (float*)carve(1536*4);
    u16* Wh    = (u16*)carve((size_t)WTOT*2);
    u16* Wl    = (u16*)carve((size_t)WTOT*2);
    u16* net1h = (u16*)carve(MTOT*128*2);      // fc_pos input; later T
    u16* net1l = (u16*)carve(MTOT*128*2);
    u16* X0h   = (u16*)carve(MTOT*256*2);      // fc_pos out; later Y ping
    u16* X0l   = (u16*)carve(MTOT*256*2);
    u16* Abh   = (u16*)carve(MTOT*256*2);      // A; also U (front half)
    u16* Abl   = (u16*)carve(MTOT*256*2);
    u16* Ybh   = (u16*)carve(MTOT*128*2);      // Y pong
    u16* Ybl   = (u16*)carve(MTOT*128*2);
    float* PmBuf[2] = { Pm0, Pm1 };

    convert_w_kernel<<<(WTOT+255)/256, 256, 0, stream>>>(
        w_fc_pos, blk_dir0, blk_fc0, blk_dir1, blk_fc1, blk_sc, Wh, Wl);
    knn_kernel<<<BB*NPT, 256, 0, stream>>>(p, idx);
    edgeconv_kernel<<<BB*NPT, 128, 0, stream>>>(p, idx, w_conv_feat, w_conv_dir, net1h, net1l);

    // fc_pos: [256 x 128] x net1 -> X0
    gemm_plain<256,128,0,false,false><<<dim3(384,2), 256, 0, stream>>>(
        Wh+WO_FCPOS, Wl+WO_FCPOS, 128, net1h, net1l, 128,
        nullptr, nullptr, 0, nullptr, nullptr, 0,
        nullptr, nullptr, X0h, X0l, 256, nullptr);

    const u16 *Yph = nullptr, *Ypl = nullptr;
    for (int i = 0; i < 5; ++i) {
        size_t od0 = WO_DIR0 + (size_t)i*65536;
        size_t of0 = WO_FC0  + (size_t)i*32768;
        size_t od1 = WO_DIR1 + (size_t)i*16384;
        size_t of1 = WO_FC1  + (size_t)i*16384;
        size_t osc = WO_SC   + (size_t)i*32768;
        float* PmPrev = PmBuf[(i+1) & 1];      // written by iteration i-1
        float* PmCur  = PmBuf[i & 1];

        // dir0 also zeroes all 1536 floats of PmCur (block 0) — replaces memset.
        if (i == 0) {
            gemm_dir<256,256,false><<<dim3(BB*64,2), 256, 0, stream>>>(
                Wh+od0, Wl+od0, 256, X0h, X0l, 256, nullptr, nullptr,
                Abh, Abl, 256, PmCur);
        } else {
            gemm_dir<256,128,true><<<dim3(BB*64,2), 256, 0, stream>>>(
                Wh+od0, Wl+od0, 256, Yph, Ypl, 128,
                blk_dir0 + (size_t)i*65536, PmPrev, Abh, Abl, 256, PmCur);
        }
        gemm_plain<128,256,0,false,false><<<dim3(384,1), 256, 0, stream>>>(
            Wh+of0, Wl+of0, 256, Abh, Abl, 256,
            nullptr, nullptr, 0, nullptr, nullptr, 0,
            nullptr, nullptr, net1h, net1l, 128, nullptr);
        gemm_dir<128,128,false><<<dim3(BB*64,1), 256, 0, stream>>>(
            Wh+od1, Wl+od1, 128, net1h, net1l, 128, nullptr, nullptr,
            Abh, Abl, 128, nullptr);

        u16* outh = (i % 2 == 0) ? Ybh : X0h;
        u16* outl = (i % 2 == 0) ? Ybl : X0l;
        if (i == 0) {
            gemm_plain<128,128,256,true,false><<<dim3(384,1), 256, 0, stream>>>(
                Wh+of1, Wl+of1, 128, Abh, Abl, 128,
                Wh+osc, Wl+osc, 256, X0h, X0l, 256,
                nullptr, nullptr, outh, outl, 128, PmCur);
        } else {
            gemm_plain<128,128,128,true,true><<<dim3(384,1), 256, 0, stream>>>(
                Wh+of1, Wl+of1, 128, Abh, Abl, 128,
                Wh+osc, Wl+osc, 256, Yph, Ypl, 128,
                blk_sc + (size_t)i*32768, PmPrev, outh, outl, 128, PmCur);
        }
        Yph = outh; Ypl = outl;
    }

    final_head_kernel<<<BB, 128, 0, stream>>>(PmBuf[0], w_actc_dir, w_fc_c, out);
}

// Round 12
// 345.434 us; speedup vs baseline: 1.6257x; 1.6257x over previous
//
#include <hip/hip_runtime.h>
#include <math.h>

#define NPT 2048
#define BB 4
#define KNN 20
#define EPSV 1e-6f

typedef unsigned short u16;
typedef unsigned int u32;
typedef _Float16 half8 __attribute__((ext_vector_type(8)));
typedef __attribute__((ext_vector_type(4))) float f32x4;
typedef __attribute__((ext_vector_type(4))) u32 uint4v;

#define MFMAH(a,b,c) __builtin_amdgcn_mfma_f32_16x16x32_f16((a),(b),(c),0,0,0)

__device__ __forceinline__ u16 f2h(float f) {
    _Float16 h = (_Float16)f;
    return __builtin_bit_cast(u16, h);
}
__device__ __forceinline__ float h2f(u16 b) {
    return (float)__builtin_bit_cast(_Float16, b);
}

// ------------------------------------------------ kNN top-20 via radix-select
// (round-7 version, verbatim — passed)
__global__ __launch_bounds__(256)
void knn_kernel(const float* __restrict__ p, int* __restrict__ idx) {
    int bn = blockIdx.x;
    int b = bn >> 11, n = bn & (NPT - 1);
    const float* pb = p + (size_t)b * NPT * 3;
    float qx = pb[n*3+0], qy = pb[n*3+1], qz = pb[n*3+2];
    float qq = qx*qx + qy*qy + qz*qz;
    __shared__ u32 keys[NPT];
    __shared__ int hist[4][256];
    __shared__ int wtot[4];
    __shared__ int sh_byte, sh_ngt, sure_cnt, tie_cnt;
    __shared__ int tie_m[64];
    int tid = threadIdx.x;
    int lane = tid & 63, wv = tid >> 6;
    for (int m = tid; m < NPT; m += 256) {
        float px = pb[m*3+0], py = pb[m*3+1], pz = pb[m*3+2];
        float sc = 2.f*(qx*px + qy*py + qz*pz) - qq - (px*px + py*py + pz*pz);
        u32 u = __builtin_bit_cast(u32, sc);
        keys[m] = u ^ (u32)(((int)u >> 31) | (int)0x80000000);
    }
    if (tid == 0) { sure_cnt = 0; tie_cnt = 0; }
    __syncthreads();
    u32 prefix = 0; int need = KNN;
    for (int pass = 3; pass >= 0; --pass) {
        int shift = pass * 8;
        u32 maskhi = (pass == 3) ? 0u : (0xFFFFFFFFu << (shift + 8));
        hist[0][tid] = 0; hist[1][tid] = 0; hist[2][tid] = 0; hist[3][tid] = 0;
        __syncthreads();
        int prevbin = -1, cnt = 0;
        #pragma unroll
        for (int j = 0; j < 8; ++j) {
            u32 key = keys[tid + 256*j];
            int bin = ((key & maskhi) == (prefix & maskhi)) ? (int)((key >> shift) & 255) : -1;
            if (bin == prevbin) { ++cnt; }
            else {
                if (prevbin >= 0) atomicAdd(&hist[wv][prevbin], cnt);
                prevbin = bin; cnt = 1;
            }
        }
        if (prevbin >= 0) atomicAdd(&hist[wv][prevbin], cnt);
        __syncthreads();
        int own = hist[0][tid] + hist[1][tid] + hist[2][tid] + hist[3][tid];
        int sum = own;
        #pragma unroll
        for (int off = 1; off < 64; off <<= 1) {
            int v = __shfl_down(sum, off, 64);
            if (lane + off < 64) sum += v;
        }
        if (lane == 0) wtot[wv] = sum;
        __syncthreads();
        int addhi = 0;
        #pragma unroll
        for (int w2 = 0; w2 < 4; ++w2) if (w2 > wv) addhi += wtot[w2];
        int cnt_ge = sum + addhi;
        int cnt_gt = cnt_ge - own;
        if (cnt_ge >= need && cnt_gt < need) { sh_byte = tid; sh_ngt = cnt_gt; }
        __syncthreads();
        prefix |= ((u32)sh_byte) << shift;
        need -= sh_ngt;
        __syncthreads();
    }
    u32 T = prefix;
    #pragma unroll
    for (int j = 0; j < 8; ++j) {
        int m = tid + 256*j;
        u32 key = keys[m];
        if (key > T) {
            int slot = atomicAdd(&sure_cnt, 1);
            idx[(size_t)bn*KNN + slot] = m;
        } else if (key == T) {
            int t = atomicAdd(&tie_cnt, 1);
            if (t < 64) tie_m[t] = m;
        }
    }
    __syncthreads();
    if (tid == 0) {
        int base = sure_cnt;
        int r = KNN - base;
        int tc = tie_cnt;
        if (tc == r) {
            for (int t2 = 0; t2 < r; ++t2) idx[(size_t)bn*KNN + base + t2] = tie_m[t2];
        } else if (tc <= 64) {
            for (int t2 = 0; t2 < r; ++t2) {
                int best = 1 << 30, bj = 0;
                for (int t3 = 0; t3 < tc; ++t3)
                    if (tie_m[t3] < best) { best = tie_m[t3]; bj = t3; }
                tie_m[bj] = 1 << 30;
                idx[(size_t)bn*KNN + base + t2] = best;
            }
        } else {
            int got = 0;
            for (int m = 0; m < NPT && got < r; ++m)
                if (keys[m] == T) { idx[(size_t)bn*KNN + base + got] = m; ++got; }
        }
    }
}

// ---------------------- edge conv + leaky(0.2) + mean_k -> fp16 K-major
__global__ __launch_bounds__(128)
void edgeconv_kernel(const float* __restrict__ p, const int* __restrict__ idx,
                     const float* __restrict__ wf, const float* __restrict__ wd,
                     u16* __restrict__ net1) {
    int bn = blockIdx.x;
    int b = bn >> 11, n = bn & (NPT - 1);
    __shared__ float nb[KNN][3];
    __shared__ float ctr[3];
    int tid = threadIdx.x;
    if (tid < KNN) {
        int j = idx[(size_t)bn*KNN + tid];
        const float* pj = p + ((size_t)b*NPT + j)*3;
        nb[tid][0] = pj[0]; nb[tid][1] = pj[1]; nb[tid][2] = pj[2];
    }
    if (tid >= 64 && tid < 67) ctr[tid-64] = p[((size_t)b*NPT + n)*3 + (tid-64)];
    __syncthreads();
    int o = tid;
    float wfa = wf[o*3+0], wfb = wf[o*3+1], wfc = wf[o*3+2];
    float wda = wd[o*3+0], wdb = wd[o*3+1], wdc = wd[o*3+2];
    float cx = ctr[0], cy = ctr[1], cz = ctr[2];
    float a0 = 0.f, a1 = 0.f, a2 = 0.f;
    #pragma unroll 4
    for (int k = 0; k < KNN; ++k) {
        float nx = nb[k][0], ny = nb[k][1], nz = nb[k][2];
        float rx = nx-cx, ry = ny-cy, rz = nz-cz;
        float sx = ny*cz - nz*cy;
        float sy = nz*cx - nx*cz;
        float sz = nx*cy - ny*cx;
        float fx = wfa*rx + wfb*cx + wfc*sx;
        float fy = wfa*ry + wfb*cy + wfc*sy;
        float fz = wfa*rz + wfb*cz + wfc*sz;
        float dx0 = wda*rx + wdb*cx + wdc*sx;
        float dy0 = wda*ry + wdb*cy + wdc*sy;
        float dz0 = wda*rz + wdb*cz + wdc*sz;
        float dot = fx*dx0 + fy*dy0 + fz*dz0;
        float dsq = dx0*dx0 + dy0*dy0 + dz0*dz0;
        float t = dot / (dsq + EPSV);
        bool pos = dot >= 0.f;
        float gx = pos ? fx : (fx - t*dx0);
        float gy = pos ? fy : (fy - t*dy0);
        float gz = pos ? fz : (fz - t*dz0);
        a0 += 0.2f*fx + 0.8f*gx;
        a1 += 0.2f*fy + 0.8f*gy;
        a2 += 0.2f*fz + 0.8f*gz;
    }
    const float s = 1.f / (float)KNN;
    float av[3] = {a0*s, a1*s, a2*s};
    #pragma unroll
    for (int v = 0; v < 3; ++v)
        net1[(size_t)(b*6144 + v*2048 + n)*128 + o] = f2h(av[v]);
}

// ------------------------------------------------------ MFMA fp16 GEMM
// Tile 128o x 64m, K-step 64, 256 thr (4 waves = 2o x 2m). LDS-staged.
template<int O, int C1, int C2, bool POOL, bool BIASED>
__global__ __launch_bounds__(256) void gemm_plain(
    const u16* __restrict__ W1, int ldw1,
    const u16* __restrict__ X1, int sx1,
    const u16* __restrict__ W2, int ldw2,
    const u16* __restrict__ X2, int sx2,
    const float* __restrict__ WscF, const float* __restrict__ PmPrev,
    u16* __restrict__ Y, int sy,
    float* __restrict__ PmOut)
{
    __shared__ __align__(16) char smem[64*132*4];   // 33792 B (stage 27648)
    __shared__ float pms[128];
    __shared__ float biasS_s[128];
    const int m0 = blockIdx.x * 64;
    const int ob = blockIdx.y * 128;
    const int b   = m0 / 6144;
    const int vec = (m0 % 6144) / 2048;
    const int tid = threadIdx.x;
    const int lane = tid & 63;
    const int wid = __builtin_amdgcn_readfirstlane(tid >> 6);
    const int wr = wid & 1, wc = wid >> 1;
    const int l15 = lane & 15, l4 = lane >> 4;

    if (BIASED) {
        if (tid < 128) pms[tid] = PmPrev[(size_t)(b*128 + tid)*3 + vec];
        __syncthreads();
        if (tid < 128) {
            const float* wrow = WscF + (size_t)tid*256 + 128;
            float s = 0.f;
            #pragma unroll 4
            for (int c = 0; c < 128; ++c) s += wrow[c]*pms[c];
            biasS_s[tid] = s;
        }
        __syncthreads();
    }

    f32x4 acc[4][2];
    #pragma unroll
    for (int io = 0; io < 4; ++io) {
        float bv[4];
        #pragma unroll
        for (int r = 0; r < 4; ++r)
            bv[r] = BIASED ? biasS_s[wr*64 + io*16 + l4*4 + r] : 0.f;
        #pragma unroll
        for (int jc = 0; jc < 2; ++jc)
            #pragma unroll
            for (int r = 0; r < 4; ++r) acc[io][jc][r] = bv[r];
    }

    constexpr int NS = (C1 + C2) / 64;
    // u-space: [0,1024) W (128 rows x 8 q); [1024,1536) X (64 rows x 8 q).
    auto ldaddr = [&](int st, int u) -> const u16* {
        const bool ph2 = (st >= C1/64);
        const u16* w = ph2 ? W2 : W1; const u16* x = ph2 ? X2 : X1;
        int ldw = ph2 ? ldw2 : ldw1; int sx = ph2 ? sx2 : sx1;
        int cc = (ph2 ? (st - C1/64) : st) * 64;
        if (u < 1024) {
            int row = u >> 3, q = u & 7;
            return w + (size_t)(ob + row)*ldw + cc + q*8;
        }
        int uu = u - 1024;
        int row = uu >> 3, q = uu & 7;
        return x + (size_t)(m0 + row)*sx + cc + q*8;
    };
    auto lds_dst = [&](int u) -> char* {
        if (u < 1024) { int row = u >> 3, q = u & 7; return smem + row*144 + q*16; }
        int uu = u - 1024;
        int row = uu >> 3, q = uu & 7;
        return smem + 18432 + row*144 + q*16;
    };

    uint4v pf[6];
    #pragma unroll
    for (int j = 0; j < 6; ++j) pf[j] = *reinterpret_cast<const uint4v*>(ldaddr(0, tid + 256*j));
    #pragma unroll
    for (int j = 0; j < 6; ++j) *reinterpret_cast<uint4v*>(lds_dst(tid + 256*j)) = pf[j];

    for (int st = 0; st < NS; ++st) {
        __syncthreads();
        if (st + 1 < NS) {
            #pragma unroll
            for (int j = 0; j < 6; ++j)
                pf[j] = *reinterpret_cast<const uint4v*>(ldaddr(st+1, tid + 256*j));
        }
        #pragma unroll
        for (int ks = 0; ks < 2; ++ks) {
            half8 fA[4], fB[2];
            #pragma unroll
            for (int io = 0; io < 4; ++io)
                fA[io] = *reinterpret_cast<const half8*>(smem + (wr*64 + io*16 + l15)*144 + ks*64 + l4*16);
            #pragma unroll
            for (int i = 0; i < 2; ++i)
                fB[i] = *reinterpret_cast<const half8*>(smem + 18432 + (wc*32 + i*16 + l15)*144 + ks*64 + l4*16);
            #pragma unroll
            for (int io = 0; io < 4; ++io)
                #pragma unroll
                for (int jc = 0; jc < 2; ++jc)
                    acc[io][jc] = MFMAH(fA[io], fB[jc], acc[io][jc]);
        }
        __syncthreads();
        if (st + 1 < NS) {
            #pragma unroll
            for (int j = 0; j < 6; ++j)
                *reinterpret_cast<uint4v*>(lds_dst(tid + 256*j)) = pf[j];
        }
    }

    float* sd = (float*)smem;
    #pragma unroll
    for (int io = 0; io < 4; ++io)
        #pragma unroll
        for (int jc = 0; jc < 2; ++jc) {
            int jj = wc*32 + jc*16 + l15;
            int orow = wr*64 + io*16 + l4*4;
            *reinterpret_cast<f32x4*>(sd + jj*132 + orow) = acc[io][jc];
        }
    __syncthreads();

    #pragma unroll
    for (int rep = 0; rep < 4; ++rep) {
        int task = tid + 256*rep;
        int oc = task & 15, ml = task >> 4;
        const float* dp = sd + ml*132 + oc*8;
        u32 hw[4];
        #pragma unroll
        for (int e2 = 0; e2 < 4; ++e2)
            hw[e2] = (u32)f2h(dp[2*e2]) | ((u32)f2h(dp[2*e2+1]) << 16);
        *reinterpret_cast<uint4v*>(Y + (size_t)(m0 + ml)*sy + ob + oc*8) =
            (uint4v){hw[0],hw[1],hw[2],hw[3]};
    }

    if (POOL) {
        int o_l = tid & 127, half = tid >> 7;
        float sum = 0.f;
        #pragma unroll 8
        for (int c = 0; c < 32; ++c) sum += sd[(half*32 + c)*132 + o_l];
        atomicAdd(&PmOut[(size_t)(b*128 + o_l)*3 + vec], sum * (1.f/(float)NPT));
    }
}

// ------------------- MFMA fp16 dir GEMM + fused VN-leaky(0) epilogue
template<int O, int CIN, bool VIRT>
__global__ __launch_bounds__(256) void gemm_dir(
    const u16* __restrict__ W_, int ldw,
    const u16* __restrict__ X1, int sx,
    const float* __restrict__ WdF, const float* __restrict__ Pm,
    u16* __restrict__ Ov, int so,
    float* __restrict__ PmZero)
{
    __shared__ __align__(16) char smem[96*132*4];   // 50688 B (stage 32256)
    __shared__ float pmd[384];
    __shared__ float biasD_s[384];
    const int gx = blockIdx.x;
    const int b  = gx >> 6;
    const int n0 = (gx & 63) * 32;
    const int ob = blockIdx.y * 128;
    const int tid = threadIdx.x;
    const int lane = tid & 63;
    const int wid = __builtin_amdgcn_readfirstlane(tid >> 6);
    const int wr = wid & 1, wc = wid >> 1;
    const int l15 = lane & 15, l4 = lane >> 4;

    if (PmZero != nullptr && gx == 0 && blockIdx.y == 0)
        for (int t = tid; t < 1536; t += 256) PmZero[t] = 0.f;

    if (VIRT) {
        for (int t = tid; t < 384; t += 256) pmd[t] = Pm[(size_t)b*384 + t];
        __syncthreads();
        for (int t = tid; t < 384; t += 256) {
            int o_l = t / 3, v = t - o_l*3;
            const float* wrow = WdF + (size_t)(ob + o_l)*256 + 128;
            float s = 0.f;
            #pragma unroll 4
            for (int c = 0; c < 128; ++c) s += wrow[c]*pmd[c*3 + v];
            biasD_s[t] = s;
        }
        __syncthreads();
    }

    f32x4 acc[4][3];
    #pragma unroll
    for (int io = 0; io < 4; ++io)
        #pragma unroll
        for (int jc = 0; jc < 3; ++jc) {
            int v = (wc*48 + jc*16) >> 5;
            #pragma unroll
            for (int r = 0; r < 4; ++r) {
                int o_l = wr*64 + io*16 + l4*4 + r;
                acc[io][jc][r] = VIRT ? biasD_s[o_l*3 + v] : 0.f;
            }
        }

    constexpr int NS = CIN / 64;
    // u-space: [0,1024) W (128x8q); [1024,1792) X (96x8q).
    auto ldaddr = [&](int st, int u) -> const u16* {
        int cc = st*64;
        if (u < 1024) {
            int row = u >> 3, q = u & 7;
            return W_ + (size_t)(ob + row)*ldw + cc + q*8;
        }
        int uu = u - 1024;
        int row = uu >> 3, q = uu & 7;
        int m = b*6144 + (row >> 5)*2048 + n0 + (row & 31);
        return X1 + (size_t)m*sx + cc + q*8;
    };
    auto lds_dst = [&](int u) -> char* {
        if (u < 1024) { int row = u >> 3, q = u & 7; return smem + row*144 + q*16; }
        int uu = u - 1024;
        int row = uu >> 3, q = uu & 7;
        return smem + 18432 + row*144 + q*16;
    };

    uint4v pf[7];
    #pragma unroll
    for (int j = 0; j < 7; ++j) pf[j] = *reinterpret_cast<const uint4v*>(ldaddr(0, tid + 256*j));
    #pragma unroll
    for (int j = 0; j < 7; ++j) *reinterpret_cast<uint4v*>(lds_dst(tid + 256*j)) = pf[j];

    for (int st = 0; st < NS; ++st) {
        __syncthreads();
        if (st + 1 < NS) {
            #pragma unroll
            for (int j = 0; j < 7; ++j)
                pf[j] = *reinterpret_cast<const uint4v*>(ldaddr(st+1, tid + 256*j));
        }
        #pragma unroll
        for (int ks = 0; ks < 2; ++ks) {
            half8 fA[4], fB[3];
            #pragma unroll
            for (int io = 0; io < 4; ++io)
                fA[io] = *reinterpret_cast<const half8*>(smem + (wr*64 + io*16 + l15)*144 + ks*64 + l4*16);
            #pragma unroll
            for (int i = 0; i < 3; ++i)
                fB[i] = *reinterpret_cast<const half8*>(smem + 18432 + (wc*48 + i*16 + l15)*144 + ks*64 + l4*16);
            #pragma unroll
            for (int io = 0; io < 4; ++io)
                #pragma unroll
                for (int jc = 0; jc < 3; ++jc)
                    acc[io][jc] = MFMAH(fA[io], fB[jc], acc[io][jc]);
        }
        __syncthreads();
        if (st + 1 < NS) {
            #pragma unroll
            for (int j = 0; j < 7; ++j)
                *reinterpret_cast<uint4v*>(lds_dst(tid + 256*j)) = pf[j];
        }
    }

    float* sd = (float*)smem;
    #pragma unroll
    for (int io = 0; io < 4; ++io)
        #pragma unroll
        for (int jc = 0; jc < 3; ++jc) {
            int jj = wc*48 + jc*16 + l15;
            int orow = wr*64 + io*16 + l4*4;
            *reinterpret_cast<f32x4*>(sd + jj*132 + orow) = acc[io][jc];
        }
    __syncthreads();

    #pragma unroll
    for (int rep = 0; rep < 2; ++rep) {
        int task = tid + 256*rep;
        int oc = task & 15, nl = (task >> 4) & 31;
        float d[3][8], x[3][8];
        #pragma unroll
        for (int v = 0; v < 3; ++v) {
            const float* dp = sd + (v*32 + nl)*132 + oc*8;
            #pragma unroll
            for (int e = 0; e < 8; ++e) d[v][e] = dp[e];
        }
        if (VIRT && ob != 0) {
            #pragma unroll
            for (int e = 0; e < 8; ++e) {
                int c = oc*8 + e;
                #pragma unroll
                for (int v = 0; v < 3; ++v)
                    x[v][e] = Pm[(size_t)(b*128 + c)*3 + v];
            }
        } else {
            #pragma unroll
            for (int v = 0; v < 3; ++v) {
                size_t m = (size_t)(b*6144 + v*2048 + n0 + nl);
                uint4v hx = *reinterpret_cast<const uint4v*>(X1 + m*sx + ob + oc*8);
                #pragma unroll
                for (int w = 0; w < 4; ++w) {
                    x[v][2*w]   = h2f((u16)(hx[w] & 0xffffu));
                    x[v][2*w+1] = h2f((u16)(hx[w] >> 16));
                }
            }
        }
        #pragma unroll
        for (int e = 0; e < 8; ++e) {
            float d0 = d[0][e], d1 = d[1][e], d2 = d[2][e];
            float dot = x[0][e]*d0 + x[1][e]*d1 + x[2][e]*d2;
            float dsq = d0*d0 + d1*d1 + d2*d2;
            float t = dot / (dsq + EPSV);
            if (dot < 0.f) { x[0][e] -= t*d0; x[1][e] -= t*d1; x[2][e] -= t*d2; }
        }
        #pragma unroll
        for (int v = 0; v < 3; ++v) {
            u32 hw[4];
            #pragma unroll
            for (int e2 = 0; e2 < 4; ++e2)
                hw[e2] = (u32)f2h(x[v][2*e2]) | ((u32)f2h(x[v][2*e2+1]) << 16);
            *reinterpret_cast<uint4v*>(Ov + (size_t)(b*6144 + v*2048 + n0 + nl)*so + ob + oc*8) =
                (uint4v){hw[0],hw[1],hw[2],hw[3]};
        }
    }
}

// ------------------------------------------------- weight fp16 convert
#define WO_FCPOS 0
#define WO_DIR0  32768
#define WO_FC0   360448
#define WO_DIR1  524288
#define WO_FC1   606208
#define WO_SC    688128
#define WTOT     851968
__global__ __launch_bounds__(256)
void convert_w_kernel(const float* __restrict__ s0, const float* __restrict__ s1,
                      const float* __restrict__ s2, const float* __restrict__ s3,
                      const float* __restrict__ s4, const float* __restrict__ s5,
                      u16* __restrict__ Wf) {
    int t = blockIdx.x*256 + threadIdx.x;
    if (t >= WTOT) return;
    const float* src; int base;
    if      (t < WO_DIR0) { src = s0; base = WO_FCPOS; }
    else if (t < WO_FC0)  { src = s1; base = WO_DIR0; }
    else if (t < WO_DIR1) { src = s2; base = WO_FC0; }
    else if (t < WO_FC1)  { src = s3; base = WO_DIR1; }
    else if (t < WO_SC)   { src = s4; base = WO_FC1; }
    else                  { src = s5; base = WO_SC; }
    Wf[t] = f2h(src[t - base]);
}

// ----------------------------------------------------- head: leaky(0.2)+fc_c
__global__ __launch_bounds__(128)
void final_head_kernel(const float* __restrict__ q, const float* __restrict__ Wdir,
                       const float* __restrict__ Wfc, float* __restrict__ out) {
    int b = blockIdx.x; int o = threadIdx.x;
    __shared__ float qs[128][3];
    __shared__ float zs[128][3];
    qs[o][0] = q[((size_t)b*128 + o)*3 + 0];
    qs[o][1] = q[((size_t)b*128 + o)*3 + 1];
    qs[o][2] = q[((size_t)b*128 + o)*3 + 2];
    __syncthreads();
    float d0 = 0.f, d1 = 0.f, d2 = 0.f;
    for (int c = 0; c < 128; ++c) {
        float w = Wdir[o*128 + c];
        d0 += w*qs[c][0]; d1 += w*qs[c][1]; d2 += w*qs[c][2];
    }
    float x0 = qs[o][0], x1 = qs[o][1], x2 = qs[o][2];
    float dot = d0*x0 + d1*x1 + d2*x2;
    float dsq = d0*d0 + d1*d1 + d2*d2;
    float t = dot / (dsq + EPSV);
    bool pos = dot >= 0.f;
    float g0 = pos ? x0 : (x0 - t*d0);
    float g1 = pos ? x1 : (x1 - t*d1);
    float g2 = pos ? x2 : (x2 - t*d2);
    zs[o][0] = 0.2f*x0 + 0.8f*g0;
    zs[o][1] = 0.2f*x1 + 0.8f*g1;
    zs[o][2] = 0.2f*x2 + 0.8f*g2;
    __syncthreads();
    float c0 = 0.f, c1 = 0.f, c2 = 0.f;
    for (int c = 0; c < 128; ++c) {
        float w = Wfc[o*128 + c];
        c0 += w*zs[c][0]; c1 += w*zs[c][1]; c2 += w*zs[c][2];
    }
    out[((size_t)b*128 + o)*3 + 0] = c0;
    out[((size_t)b*128 + o)*3 + 1] = c1;
    out[((size_t)b*128 + o)*3 + 2] = c2;
}

extern "C" void kernel_launch(void* const* d_in, const int* in_sizes, int n_in,
                              void* d_out, int out_size, void* d_ws, size_t ws_size,
                              hipStream_t stream) {
    const float* p           = (const float*)d_in[0];
    const float* w_conv_feat = (const float*)d_in[1];
    const float* w_conv_dir  = (const float*)d_in[2];
    const float* w_fc_pos    = (const float*)d_in[3];
    const float* blk_dir0    = (const float*)d_in[4];
    const float* blk_fc0     = (const float*)d_in[5];
    const float* blk_dir1    = (const float*)d_in[6];
    const float* blk_fc1     = (const float*)d_in[7];
    const float* blk_sc      = (const float*)d_in[8];
    const float* w_actc_dir  = (const float*)d_in[9];
    const float* w_fc_c      = (const float*)d_in[10];
    float* out = (float*)d_out;

    char* wsb = (char*)d_ws;
    size_t cur = 0;
    auto carve = [&](size_t nbytes) -> char* {
        char* r = wsb + cur;
        cur += (nbytes + 255) & ~(size_t)255;
        return r;
    };
    const size_t MTOT = (size_t)BB*3*NPT;      // 24576 columns
    int*   idx   = (int*)  carve((size_t)BB*NPT*KNN*4);
    float* Pm0   = (float*)carve(1536*4);
    float* Pm1   = (float*)carve(1536*4);
    u16* Wf    = (u16*)carve((size_t)WTOT*2);
    u16* net1  = (u16*)carve(MTOT*128*2);      // fc_pos input; later T
    u16* X0    = (u16*)carve(MTOT*256*2);      // fc_pos out; later Y ping
    u16* Ab    = (u16*)carve(MTOT*256*2);      // A; also U (front half)
    u16* Yb    = (u16*)carve(MTOT*128*2);      // Y pong
    float* PmBuf[2] = { Pm0, Pm1 };

    convert_w_kernel<<<(WTOT+255)/256, 256, 0, stream>>>(
        w_fc_pos, blk_dir0, blk_fc0, blk_dir1, blk_fc1, blk_sc, Wf);
    knn_kernel<<<BB*NPT, 256, 0, stream>>>(p, idx);
    edgeconv_kernel<<<BB*NPT, 128, 0, stream>>>(p, idx, w_conv_feat, w_conv_dir, net1);

    // fc_pos: [256 x 128] x net1 -> X0
    gemm_plain<256,128,0,false,false><<<dim3(384,2), 256, 0, stream>>>(
        Wf+WO_FCPOS, 128, net1, 128,
        nullptr, 0, nullptr, 0,
        nullptr, nullptr, X0, 256, nullptr);

    const u16* Yp = nullptr;
    for (int i = 0; i < 5; ++i) {
        size_t od0 = WO_DIR0 + (size_t)i*65536;
        size_t of0 = WO_FC0  + (size_t)i*32768;
        size_t od1 = WO_DIR1 + (size_t)i*16384;
        size_t of1 = WO_FC1  + (size_t)i*16384;
        size_t osc = WO_SC   + (size_t)i*32768;
        float* PmPrev = PmBuf[(i+1) & 1];
        float* PmCur  = PmBuf[i & 1];

        // dir0 also zeroes all 1536 floats of PmCur (block 0) — replaces memset.
        if (i == 0) {
            gemm_dir<256,256,false><<<dim3(BB*64,2), 256, 0, stream>>>(
                Wf+od0, 256, X0, 256, nullptr, nullptr, Ab, 256, PmCur);
        } else {
            gemm_dir<256,128,true><<<dim3(BB*64,2), 256, 0, stream>>>(
                Wf+od0, 256, Yp, 128,
                blk_dir0 + (size_t)i*65536, PmPrev, Ab, 256, PmCur);
        }
        gemm_plain<128,256,0,false,false><<<dim3(384,1), 256, 0, stream>>>(
            Wf+of0, 256, Ab, 256,
            nullptr, 0, nullptr, 0,
            nullptr, nullptr, net1, 128, nullptr);
        gemm_dir<128,128,false><<<dim3(BB*64,1), 256, 0, stream>>>(
            Wf+od1, 128, net1, 128, nullptr, nullptr, Ab, 128, nullptr);

        u16* outv = (i % 2 == 0) ? Yb : X0;
        if (i == 0) {
            gemm_plain<128,128,256,true,false><<<dim3(384,1), 256, 0, stream>>>(
                Wf+of1, 128, Ab, 128,
                Wf+osc, 256, X0, 256,
                nullptr, nullptr, outv, 128, PmCur);
        } else {
            gemm_plain<128,128,128,true,true><<<dim3(384,1), 256, 0, stream>>>(
                Wf+of1, 128, Ab, 128,
                Wf+osc, 256, Yp, 128,
                blk_sc + (size_t)i*32768, PmPrev, outv, 128, PmCur);
        }
        Yp = outv;
    }

    final_head_kernel<<<BB, 128, 0, stream>>>(PmBuf[0], w_actc_dir, w_fc_c, out);
}

// Round 13
// 340.024 us; speedup vs baseline: 1.6515x; 1.0159x over previous
//
#include <hip/hip_runtime.h>
#include <math.h>

#define NPT 2048
#define BB 4
#define KNN 20
#define EPSV 1e-6f

typedef unsigned short u16;
typedef unsigned int u32;
typedef _Float16 half8 __attribute__((ext_vector_type(8)));
typedef __attribute__((ext_vector_type(4))) float f32x4;
typedef __attribute__((ext_vector_type(4))) u32 uint4v;

#define MFMAH(a,b,c) __builtin_amdgcn_mfma_f32_16x16x32_f16((a),(b),(c),0,0,0)

__device__ __forceinline__ u16 f2h(float f) {
    _Float16 h = (_Float16)f;
    return __builtin_bit_cast(u16, h);
}
__device__ __forceinline__ float h2f(u16 b) {
    return (float)__builtin_bit_cast(_Float16, b);
}

// -------------------- kNN top-20 (radix-select) + fused edge conv + mean_k
// Selection logic identical to the round-7/12 version (passed 4x); edgeconv
// epilogue runs in-block on the LDS-resident selection (ctr == query point).
__global__ __launch_bounds__(256)
void knn_edge_kernel(const float* __restrict__ p,
                     const float* __restrict__ wf, const float* __restrict__ wd,
                     u16* __restrict__ net1) {
    int bn = blockIdx.x;
    int b = bn >> 11, n = bn & (NPT - 1);
    const float* pb = p + (size_t)b * NPT * 3;
    float qx = pb[n*3+0], qy = pb[n*3+1], qz = pb[n*3+2];
    float qq = qx*qx + qy*qy + qz*qz;
    __shared__ u32 keys[NPT];
    __shared__ int hist[4][256];
    __shared__ int wtot[4];
    __shared__ int sh_byte, sh_ngt, sure_cnt, tie_cnt;
    __shared__ int tie_m[64];
    __shared__ int sel[KNN];
    __shared__ float nb[KNN][3];
    int tid = threadIdx.x;
    int lane = tid & 63, wv = tid >> 6;
    for (int m = tid; m < NPT; m += 256) {
        float px = pb[m*3+0], py = pb[m*3+1], pz = pb[m*3+2];
        float sc = 2.f*(qx*px + qy*py + qz*pz) - qq - (px*px + py*py + pz*pz);
        u32 u = __builtin_bit_cast(u32, sc);
        keys[m] = u ^ (u32)(((int)u >> 31) | (int)0x80000000);
    }
    if (tid == 0) { sure_cnt = 0; tie_cnt = 0; }
    __syncthreads();
    u32 prefix = 0; int need = KNN;
    for (int pass = 3; pass >= 0; --pass) {
        int shift = pass * 8;
        u32 maskhi = (pass == 3) ? 0u : (0xFFFFFFFFu << (shift + 8));
        hist[0][tid] = 0; hist[1][tid] = 0; hist[2][tid] = 0; hist[3][tid] = 0;
        __syncthreads();
        int prevbin = -1, cnt = 0;
        #pragma unroll
        for (int j = 0; j < 8; ++j) {
            u32 key = keys[tid + 256*j];
            int bin = ((key & maskhi) == (prefix & maskhi)) ? (int)((key >> shift) & 255) : -1;
            if (bin == prevbin) { ++cnt; }
            else {
                if (prevbin >= 0) atomicAdd(&hist[wv][prevbin], cnt);
                prevbin = bin; cnt = 1;
            }
        }
        if (prevbin >= 0) atomicAdd(&hist[wv][prevbin], cnt);
        __syncthreads();
        int own = hist[0][tid] + hist[1][tid] + hist[2][tid] + hist[3][tid];
        int sum = own;
        #pragma unroll
        for (int off = 1; off < 64; off <<= 1) {
            int v = __shfl_down(sum, off, 64);
            if (lane + off < 64) sum += v;
        }
        if (lane == 0) wtot[wv] = sum;
        __syncthreads();
        int addhi = 0;
        #pragma unroll
        for (int w2 = 0; w2 < 4; ++w2) if (w2 > wv) addhi += wtot[w2];
        int cnt_ge = sum + addhi;
        int cnt_gt = cnt_ge - own;
        if (cnt_ge >= need && cnt_gt < need) { sh_byte = tid; sh_ngt = cnt_gt; }
        __syncthreads();
        prefix |= ((u32)sh_byte) << shift;
        need -= sh_ngt;
        __syncthreads();
    }
    u32 T = prefix;
    #pragma unroll
    for (int j = 0; j < 8; ++j) {
        int m = tid + 256*j;
        u32 key = keys[m];
        if (key > T) {
            int slot = atomicAdd(&sure_cnt, 1);
            sel[slot] = m;
        } else if (key == T) {
            int t = atomicAdd(&tie_cnt, 1);
            if (t < 64) tie_m[t] = m;
        }
    }
    __syncthreads();
    if (tid == 0) {
        int base = sure_cnt;
        int r = KNN - base;
        int tc = tie_cnt;
        if (tc == r) {
            for (int t2 = 0; t2 < r; ++t2) sel[base + t2] = tie_m[t2];
        } else if (tc <= 64) {
            for (int t2 = 0; t2 < r; ++t2) {
                int best = 1 << 30, bj = 0;
                for (int t3 = 0; t3 < tc; ++t3)
                    if (tie_m[t3] < best) { best = tie_m[t3]; bj = t3; }
                tie_m[bj] = 1 << 30;
                sel[base + t2] = best;
            }
        } else {
            int got = 0;
            for (int m = 0; m < NPT && got < r; ++m)
                if (keys[m] == T) { sel[base + got] = m; ++got; }
        }
    }
    __syncthreads();
    if (tid < KNN) {
        int j = sel[tid];
        nb[tid][0] = pb[j*3+0]; nb[tid][1] = pb[j*3+1]; nb[tid][2] = pb[j*3+2];
    }
    __syncthreads();
    if (tid < 128) {
        int o = tid;
        float wfa = wf[o*3+0], wfb = wf[o*3+1], wfc = wf[o*3+2];
        float wda = wd[o*3+0], wdb = wd[o*3+1], wdc = wd[o*3+2];
        float cx = qx, cy = qy, cz = qz;
        float a0 = 0.f, a1 = 0.f, a2 = 0.f;
        #pragma unroll 4
        for (int k = 0; k < KNN; ++k) {
            float nx = nb[k][0], ny = nb[k][1], nz = nb[k][2];
            float rx = nx-cx, ry = ny-cy, rz = nz-cz;
            float sx = ny*cz - nz*cy;
            float sy = nz*cx - nx*cz;
            float sz = nx*cy - ny*cx;
            float fx = wfa*rx + wfb*cx + wfc*sx;
            float fy = wfa*ry + wfb*cy + wfc*sy;
            float fz = wfa*rz + wfb*cz + wfc*sz;
            float dx0 = wda*rx + wdb*cx + wdc*sx;
            float dy0 = wda*ry + wdb*cy + wdc*sy;
            float dz0 = wda*rz + wdb*cz + wdc*sz;
            float dot = fx*dx0 + fy*dy0 + fz*dz0;
            float dsq = dx0*dx0 + dy0*dy0 + dz0*dz0;
            float t = dot / (dsq + EPSV);
            bool pos = dot >= 0.f;
            float gx = pos ? fx : (fx - t*dx0);
            float gy = pos ? fy : (fy - t*dy0);
            float gz = pos ? fz : (fz - t*dz0);
            a0 += 0.2f*fx + 0.8f*gx;
            a1 += 0.2f*fy + 0.8f*gy;
            a2 += 0.2f*fz + 0.8f*gz;
        }
        const float s = 1.f / (float)KNN;
        net1[(size_t)(b*6144 +          n)*128 + o] = f2h(a0*s);
        net1[(size_t)(b*6144 + 2048  + n)*128 + o] = f2h(a1*s);
        net1[(size_t)(b*6144 + 4096  + n)*128 + o] = f2h(a2*s);
    }
}

// ------------------------------------------------------ MFMA fp16 GEMM
// Tile 128o x 64m, K-step 64, 256 thr (4 waves = 2o x 2m). LDS-staged.
template<int O, int C1, int C2, bool POOL, bool BIASED>
__global__ __launch_bounds__(256) void gemm_plain(
    const u16* __restrict__ W1, int ldw1,
    const u16* __restrict__ X1, int sx1,
    const u16* __restrict__ W2, int ldw2,
    const u16* __restrict__ X2, int sx2,
    const float* __restrict__ WscF, const float* __restrict__ PmPrev,
    u16* __restrict__ Y, int sy,
    float* __restrict__ PmOut)
{
    __shared__ __align__(16) char smem[64*132*4];
    __shared__ float pms[128];
    __shared__ float biasS_s[128];
    const int m0 = blockIdx.x * 64;
    const int ob = blockIdx.y * 128;
    const int b   = m0 / 6144;
    const int vec = (m0 % 6144) / 2048;
    const int tid = threadIdx.x;
    const int lane = tid & 63;
    const int wid = __builtin_amdgcn_readfirstlane(tid >> 6);
    const int wr = wid & 1, wc = wid >> 1;
    const int l15 = lane & 15, l4 = lane >> 4;

    if (BIASED) {
        if (tid < 128) pms[tid] = PmPrev[(size_t)(b*128 + tid)*3 + vec];
        __syncthreads();
        if (tid < 128) {
            const float* wrow = WscF + (size_t)tid*256 + 128;
            float s = 0.f;
            #pragma unroll 4
            for (int c = 0; c < 128; ++c) s += wrow[c]*pms[c];
            biasS_s[tid] = s;
        }
        __syncthreads();
    }

    f32x4 acc[4][2];
    #pragma unroll
    for (int io = 0; io < 4; ++io) {
        float bv[4];
        #pragma unroll
        for (int r = 0; r < 4; ++r)
            bv[r] = BIASED ? biasS_s[wr*64 + io*16 + l4*4 + r] : 0.f;
        #pragma unroll
        for (int jc = 0; jc < 2; ++jc)
            #pragma unroll
            for (int r = 0; r < 4; ++r) acc[io][jc][r] = bv[r];
    }

    constexpr int NS = (C1 + C2) / 64;
    auto ldaddr = [&](int st, int u) -> const u16* {
        const bool ph2 = (st >= C1/64);
        const u16* w = ph2 ? W2 : W1; const u16* x = ph2 ? X2 : X1;
        int ldw = ph2 ? ldw2 : ldw1; int sx = ph2 ? sx2 : sx1;
        int cc = (ph2 ? (st - C1/64) : st) * 64;
        if (u < 1024) {
            int row = u >> 3, q = u & 7;
            return w + (size_t)(ob + row)*ldw + cc + q*8;
        }
        int uu = u - 1024;
        int row = uu >> 3, q = uu & 7;
        return x + (size_t)(m0 + row)*sx + cc + q*8;
    };
    auto lds_dst = [&](int u) -> char* {
        if (u < 1024) { int row = u >> 3, q = u & 7; return smem + row*144 + q*16; }
        int uu = u - 1024;
        int row = uu >> 3, q = uu & 7;
        return smem + 18432 + row*144 + q*16;
    };

    uint4v pf[6];
    #pragma unroll
    for (int j = 0; j < 6; ++j) pf[j] = *reinterpret_cast<const uint4v*>(ldaddr(0, tid + 256*j));
    #pragma unroll
    for (int j = 0; j < 6; ++j) *reinterpret_cast<uint4v*>(lds_dst(tid + 256*j)) = pf[j];

    for (int st = 0; st < NS; ++st) {
        __syncthreads();
        if (st + 1 < NS) {
            #pragma unroll
            for (int j = 0; j < 6; ++j)
                pf[j] = *reinterpret_cast<const uint4v*>(ldaddr(st+1, tid + 256*j));
        }
        #pragma unroll
        for (int ks = 0; ks < 2; ++ks) {
            half8 fA[4], fB[2];
            #pragma unroll
            for (int io = 0; io < 4; ++io)
                fA[io] = *reinterpret_cast<const half8*>(smem + (wr*64 + io*16 + l15)*144 + ks*64 + l4*16);
            #pragma unroll
            for (int i = 0; i < 2; ++i)
                fB[i] = *reinterpret_cast<const half8*>(smem + 18432 + (wc*32 + i*16 + l15)*144 + ks*64 + l4*16);
            #pragma unroll
            for (int io = 0; io < 4; ++io)
                #pragma unroll
                for (int jc = 0; jc < 2; ++jc)
                    acc[io][jc] = MFMAH(fA[io], fB[jc], acc[io][jc]);
        }
        __syncthreads();
        if (st + 1 < NS) {
            #pragma unroll
            for (int j = 0; j < 6; ++j)
                *reinterpret_cast<uint4v*>(lds_dst(tid + 256*j)) = pf[j];
        }
    }

    float* sd = (float*)smem;
    #pragma unroll
    for (int io = 0; io < 4; ++io)
        #pragma unroll
        for (int jc = 0; jc < 2; ++jc) {
            int jj = wc*32 + jc*16 + l15;
            int orow = wr*64 + io*16 + l4*4;
            *reinterpret_cast<f32x4*>(sd + jj*132 + orow) = acc[io][jc];
        }
    __syncthreads();

    #pragma unroll
    for (int rep = 0; rep < 4; ++rep) {
        int task = tid + 256*rep;
        int oc = task & 15, ml = task >> 4;
        const float* dp = sd + ml*132 + oc*8;
        u32 hw[4];
        #pragma unroll
        for (int e2 = 0; e2 < 4; ++e2)
            hw[e2] = (u32)f2h(dp[2*e2]) | ((u32)f2h(dp[2*e2+1]) << 16);
        *reinterpret_cast<uint4v*>(Y + (size_t)(m0 + ml)*sy + ob + oc*8) =
            (uint4v){hw[0],hw[1],hw[2],hw[3]};
    }

    if (POOL) {
        int o_l = tid & 127, half = tid >> 7;
        float sum = 0.f;
        #pragma unroll 8
        for (int c = 0; c < 32; ++c) sum += sd[(half*32 + c)*132 + o_l];
        atomicAdd(&PmOut[(size_t)(b*128 + o_l)*3 + vec], sum * (1.f/(float)NPT));
    }
}

// ------------------- MFMA fp16 dir GEMM + fused VN-leaky(0) epilogue
template<int O, int CIN, bool VIRT>
__global__ __launch_bounds__(256) void gemm_dir(
    const u16* __restrict__ W_, int ldw,
    const u16* __restrict__ X1, int sx,
    const float* __restrict__ WdF, const float* __restrict__ Pm,
    u16* __restrict__ Ov, int so,
    float* __restrict__ PmZero)
{
    __shared__ __align__(16) char smem[96*132*4];
    __shared__ float pmd[384];
    __shared__ float biasD_s[384];
    const int gx = blockIdx.x;
    const int b  = gx >> 6;
    const int n0 = (gx & 63) * 32;
    const int ob = blockIdx.y * 128;
    const int tid = threadIdx.x;
    const int lane = tid & 63;
    const int wid = __builtin_amdgcn_readfirstlane(tid >> 6);
    const int wr = wid & 1, wc = wid >> 1;
    const int l15 = lane & 15, l4 = lane >> 4;

    if (PmZero != nullptr && gx == 0 && blockIdx.y == 0)
        for (int t = tid; t < 1536; t += 256) PmZero[t] = 0.f;

    if (VIRT) {
        for (int t = tid; t < 384; t += 256) pmd[t] = Pm[(size_t)b*384 + t];
        __syncthreads();
        for (int t = tid; t < 384; t += 256) {
            int o_l = t / 3, v = t - o_l*3;
            const float* wrow = WdF + (size_t)(ob + o_l)*256 + 128;
            float s = 0.f;
            #pragma unroll 4
            for (int c = 0; c < 128; ++c) s += wrow[c]*pmd[c*3 + v];
            biasD_s[t] = s;
        }
        __syncthreads();
    }

    f32x4 acc[4][3];
    #pragma unroll
    for (int io = 0; io < 4; ++io)
        #pragma unroll
        for (int jc = 0; jc < 3; ++jc) {
            int v = (wc*48 + jc*16) >> 5;
            #pragma unroll
            for (int r = 0; r < 4; ++r) {
                int o_l = wr*64 + io*16 + l4*4 + r;
                acc[io][jc][r] = VIRT ? biasD_s[o_l*3 + v] : 0.f;
            }
        }

    constexpr int NS = CIN / 64;
    auto ldaddr = [&](int st, int u) -> const u16* {
        int cc = st*64;
        if (u < 1024) {
            int row = u >> 3, q = u & 7;
            return W_ + (size_t)(ob + row)*ldw + cc + q*8;
        }
        int uu = u - 1024;
        int row = uu >> 3, q = uu & 7;
        int m = b*6144 + (row >> 5)*2048 + n0 + (row & 31);
        return X1 + (size_t)m*sx + cc + q*8;
    };
    auto lds_dst = [&](int u) -> char* {
        if (u < 1024) { int row = u >> 3, q = u & 7; return smem + row*144 + q*16; }
        int uu = u - 1024;
        int row = uu >> 3, q = uu & 7;
        return smem + 18432 + row*144 + q*16;
    };

    uint4v pf[7];
    #pragma unroll
    for (int j = 0; j < 7; ++j) pf[j] = *reinterpret_cast<const uint4v*>(ldaddr(0, tid + 256*j));
    #pragma unroll
    for (int j = 0; j < 7; ++j) *reinterpret_cast<uint4v*>(lds_dst(tid + 256*j)) = pf[j];

    for (int st = 0; st < NS; ++st) {
        __syncthreads();
        if (st + 1 < NS) {
            #pragma unroll
            for (int j = 0; j < 7; ++j)
                pf[j] = *reinterpret_cast<const uint4v*>(ldaddr(st+1, tid + 256*j));
        }
        #pragma unroll
        for (int ks = 0; ks < 2; ++ks) {
            half8 fA[4], fB[3];
            #pragma unroll
            for (int io = 0; io < 4; ++io)
                fA[io] = *reinterpret_cast<const half8*>(smem + (wr*64 + io*16 + l15)*144 + ks*64 + l4*16);
            #pragma unroll
            for (int i = 0; i < 3; ++i)
                fB[i] = *reinterpret_cast<const half8*>(smem + 18432 + (wc*48 + i*16 + l15)*144 + ks*64 + l4*16);
            #pragma unroll
            for (int io = 0; io < 4; ++io)
                #pragma unroll
                for (int jc = 0; jc < 3; ++jc)
                    acc[io][jc] = MFMAH(fA[io], fB[jc], acc[io][jc]);
        }
        __syncthreads();
        if (st + 1 < NS) {
            #pragma unroll
            for (int j = 0; j < 7; ++j)
                *reinterpret_cast<uint4v*>(lds_dst(tid + 256*j)) = pf[j];
        }
    }

    float* sd = (float*)smem;
    #pragma unroll
    for (int io = 0; io < 4; ++io)
        #pragma unroll
        for (int jc = 0; jc < 3; ++jc) {
            int jj = wc*48 + jc*16 + l15;
            int orow = wr*64 + io*16 + l4*4;
            *reinterpret_cast<f32x4*>(sd + jj*132 + orow) = acc[io][jc];
        }
    __syncthreads();

    #pragma unroll
    for (int rep = 0; rep < 2; ++rep) {
        int task = tid + 256*rep;
        int oc = task & 15, nl = (task >> 4) & 31;
        float d[3][8], x[3][8];
        #pragma unroll
        for (int v = 0; v < 3; ++v) {
            const float* dp = sd + (v*32 + nl)*132 + oc*8;
            #pragma unroll
            for (int e = 0; e < 8; ++e) d[v][e] = dp[e];
        }
        if (VIRT && ob != 0) {
            #pragma unroll
            for (int e = 0; e < 8; ++e) {
                int c = oc*8 + e;
                #pragma unroll
                for (int v = 0; v < 3; ++v)
                    x[v][e] = Pm[(size_t)(b*128 + c)*3 + v];
            }
        } else {
            #pragma unroll
            for (int v = 0; v < 3; ++v) {
                size_t m = (size_t)(b*6144 + v*2048 + n0 + nl);
                uint4v hx = *reinterpret_cast<const uint4v*>(X1 + m*sx + ob + oc*8);
                #pragma unroll
                for (int w = 0; w < 4; ++w) {
                    x[v][2*w]   = h2f((u16)(hx[w] & 0xffffu));
                    x[v][2*w+1] = h2f((u16)(hx[w] >> 16));
                }
            }
        }
        #pragma unroll
        for (int e = 0; e < 8; ++e) {
            float d0 = d[0][e], d1 = d[1][e], d2 = d[2][e];
            float dot = x[0][e]*d0 + x[1][e]*d1 + x[2][e]*d2;
            float dsq = d0*d0 + d1*d1 + d2*d2;
            float t = dot / (dsq + EPSV);
            if (dot < 0.f) { x[0][e] -= t*d0; x[1][e] -= t*d1; x[2][e] -= t*d2; }
        }
        #pragma unroll
        for (int v = 0; v < 3; ++v) {
            u32 hw[4];
            #pragma unroll
            for (int e2 = 0; e2 < 4; ++e2)
                hw[e2] = (u32)f2h(x[v][2*e2]) | ((u32)f2h(x[v][2*e2+1]) << 16);
            *reinterpret_cast<uint4v*>(Ov + (size_t)(b*6144 + v*2048 + n0 + nl)*so + ob + oc*8) =
                (uint4v){hw[0],hw[1],hw[2],hw[3]};
        }
    }
}

// ------------------------------------------------- weight fp16 convert
#define WO_FCPOS 0
#define WO_DIR0  32768
#define WO_FC0   360448
#define WO_DIR1  524288
#define WO_FC1   606208
#define WO_SC    688128
#define WTOT     851968
__global__ __launch_bounds__(256)
void convert_w_kernel(const float* __restrict__ s0, const float* __restrict__ s1,
                      const float* __restrict__ s2, const float* __restrict__ s3,
                      const float* __restrict__ s4, const float* __restrict__ s5,
                      u16* __restrict__ Wf) {
    int t = blockIdx.x*256 + threadIdx.x;
    if (t >= WTOT) return;
    const float* src; int base;
    if      (t < WO_DIR0) { src = s0; base = WO_FCPOS; }
    else if (t < WO_FC0)  { src = s1; base = WO_DIR0; }
    else if (t < WO_DIR1) { src = s2; base = WO_FC0; }
    else if (t < WO_FC1)  { src = s3; base = WO_DIR1; }
    else if (t < WO_SC)   { src = s4; base = WO_FC1; }
    else                  { src = s5; base = WO_SC; }
    Wf[t] = f2h(src[t - base]);
}

// ----------------------------------------------------- head: leaky(0.2)+fc_c
__global__ __launch_bounds__(128)
void final_head_kernel(const float* __restrict__ q, const float* __restrict__ Wdir,
                       const float* __restrict__ Wfc, float* __restrict__ out) {
    int b = blockIdx.x; int o = threadIdx.x;
    __shared__ float qs[128][3];
    __shared__ float zs[128][3];
    qs[o][0] = q[((size_t)b*128 + o)*3 + 0];
    qs[o][1] = q[((size_t)b*128 + o)*3 + 1];
    qs[o][2] = q[((size_t)b*128 + o)*3 + 2];
    __syncthreads();
    float d0 = 0.f, d1 = 0.f, d2 = 0.f;
    for (int c = 0; c < 128; ++c) {
        float w = Wdir[o*128 + c];
        d0 += w*qs[c][0]; d1 += w*qs[c][1]; d2 += w*qs[c][2];
    }
    float x0 = qs[o][0], x1 = qs[o][1], x2 = qs[o][2];
    float dot = d0*x0 + d1*x1 + d2*x2;
    float dsq = d0*d0 + d1*d1 + d2*d2;
    float t = dot / (dsq + EPSV);
    bool pos = dot >= 0.f;
    float g0 = pos ? x0 : (x0 - t*d0);
    float g1 = pos ? x1 : (x1 - t*d1);
    float g2 = pos ? x2 : (x2 - t*d2);
    zs[o][0] = 0.2f*x0 + 0.8f*g0;
    zs[o][1] = 0.2f*x1 + 0.8f*g1;
    zs[o][2] = 0.2f*x2 + 0.8f*g2;
    __syncthreads();
    float c0 = 0.f, c1 = 0.f, c2 = 0.f;
    for (int c = 0; c < 128; ++c) {
        float w = Wfc[o*128 + c];
        c0 += w*zs[c][0]; c1 += w*zs[c][1]; c2 += w*zs[c][2];
    }
    out[((size_t)b*128 + o)*3 + 0] = c0;
    out[((size_t)b*128 + o)*3 + 1] = c1;
    out[((size_t)b*128 + o)*3 + 2] = c2;
}

extern "C" void kernel_launch(void* const* d_in, const int* in_sizes, int n_in,
                              void* d_out, int out_size, void* d_ws, size_t ws_size,
                              hipStream_t stream) {
    const float* p           = (const float*)d_in[0];
    const float* w_conv_feat = (const float*)d_in[1];
    const float* w_conv_dir  = (const float*)d_in[2];
    const float* w_fc_pos    = (const float*)d_in[3];
    const float* blk_dir0    = (const float*)d_in[4];
    const float* blk_fc0     = (const float*)d_in[5];
    const float* blk_dir1    = (const float*)d_in[6];
    const float* blk_fc1     = (const float*)d_in[7];
    const float* blk_sc      = (const float*)d_in[8];
    const float* w_actc_dir  = (const float*)d_in[9];
    const float* w_fc_c      = (const float*)d_in[10];
    float* out = (float*)d_out;

    char* wsb = (char*)d_ws;
    size_t cur = 0;
    auto carve = [&](size_t nbytes) -> char* {
        char* r = wsb + cur;
        cur += (nbytes + 255) & ~(size_t)255;
        return r;
    };
    const size_t MTOT = (size_t)BB*3*NPT;      // 24576 columns
    float* Pm0   = (float*)carve(1536*4);
    float* Pm1   = (float*)carve(1536*4);
    u16* Wf    = (u16*)carve((size_t)WTOT*2);
    u16* net1  = (u16*)carve(MTOT*128*2);      // fc_pos input; later T
    u16* X0    = (u16*)carve(MTOT*256*2);      // fc_pos out; later Y ping
    u16* Ab    = (u16*)carve(MTOT*256*2);      // A; also U
    u16* Yb    = (u16*)carve(MTOT*128*2);      // Y pong
    float* PmBuf[2] = { Pm0, Pm1 };

    convert_w_kernel<<<(WTOT+255)/256, 256, 0, stream>>>(
        w_fc_pos, blk_dir0, blk_fc0, blk_dir1, blk_fc1, blk_sc, Wf);
    knn_edge_kernel<<<BB*NPT, 256, 0, stream>>>(p, w_conv_feat, w_conv_dir, net1);

    // fc_pos: [256 x 128] x net1 -> X0
    gemm_plain<256,128,0,false,false><<<dim3(384,2), 256, 0, stream>>>(
        Wf+WO_FCPOS, 128, net1, 128,
        nullptr, 0, nullptr, 0,
        nullptr, nullptr, X0, 256, nullptr);

    const u16* Yp = nullptr;
    for (int i = 0; i < 5; ++i) {
        size_t od0 = WO_DIR0 + (size_t)i*65536;
        size_t of0 = WO_FC0  + (size_t)i*32768;
        size_t od1 = WO_DIR1 + (size_t)i*16384;
        size_t of1 = WO_FC1  + (size_t)i*16384;
        size_t osc = WO_SC   + (size_t)i*32768;
        float* PmPrev = PmBuf[(i+1) & 1];
        float* PmCur  = PmBuf[i & 1];

        // dir0 also zeroes all 1536 floats of PmCur (block 0) — replaces memset.
        if (i == 0) {
            gemm_dir<256,256,false><<<dim3(BB*64,2), 256, 0, stream>>>(
                Wf+od0, 256, X0, 256, nullptr, nullptr, Ab, 256, PmCur);
        } else {
            gemm_dir<256,128,true><<<dim3(BB*64,2), 256, 0, stream>>>(
                Wf+od0, 256, Yp, 128,
                blk_dir0 + (size_t)i*65536, PmPrev, Ab, 256, PmCur);
        }
        gemm_plain<128,256,0,false,false><<<dim3(384,1), 256, 0, stream>>>(
            Wf+of0, 256, Ab, 256,
            nullptr, 0, nullptr, 0,
            nullptr, nullptr, net1, 128, nullptr);
        gemm_dir<128,128,false><<<dim3(BB*64,1), 256, 0, stream>>>(
            Wf+od1, 128, net1, 128, nullptr, nullptr, Ab, 128, nullptr);

        u16* outv = (i % 2 == 0) ? Yb : X0;
        if (i == 0) {
            gemm_plain<128,128,256,true,false><<<dim3(384,1), 256, 0, stream>>>(
                Wf+of1, 128, Ab, 128,
                Wf+osc, 256, X0, 256,
                nullptr, nullptr, outv, 128, PmCur);
        } else {
            gemm_plain<128,128,128,true,true><<<dim3(384,1), 256, 0, stream>>>(
                Wf+of1, 128, Ab, 128,
                Wf+osc, 256, Yp, 128,
                blk_sc + (size_t)i*32768, PmPrev, outv, 128, PmCur);
        }
        Yp = outv;
    }

    final_head_kernel<<<BB, 128, 0, stream>>>(PmBuf[0], w_actc_dir, w_fc_c, out);
}